// Round 13
// baseline (568.958 us; speedup 1.0000x reference)
//
#include <hip/hip_runtime.h>
#include <hip/hip_bf16.h>

typedef unsigned short u16;
typedef unsigned int   u32;

#define B_N   256
#define S_N   512
#define BSN   (B_N * S_N)      // 131072 positions
#define MEMN  32
#define DKN   128
#define DVN   128
#define DSN   256

typedef __attribute__((ext_vector_type(8))) short bf16x8;
typedef __attribute__((ext_vector_type(4))) float f32x4;

// ---------- helpers ----------
__device__ __forceinline__ float bf2f(u16 u) {
  union { u32 i; float f; } v; v.i = ((u32)u) << 16; return v.f;
}
__device__ __forceinline__ u16 f2bf(float f) {
  union { float f; u32 i; } v; v.f = f;
  u32 x = v.i;
  x += 0x7fffu + ((x >> 16) & 1u);   // RNE
  return (u16)(x >> 16);
}
__device__ __forceinline__ u32 pack2(float a, float b) {
  return (u32)f2bf(a) | ((u32)f2bf(b) << 16);
}
__device__ __forceinline__ float sigmoid_fast(float x) { return 1.f / (1.f + __expf(-x)); }
__device__ __forceinline__ float tanh_fast(float x)    { return 1.f - 2.f / (__expf(2.f * x) + 1.f); }

#define GLOAD_LDS16(g, l)                                         \
  __builtin_amdgcn_global_load_lds(                               \
      (const __attribute__((address_space(1))) void*)(g),         \
      (__attribute__((address_space(3))) void*)(l), 16, 0, 0)

// ============================================================
// kPrep: transpose + bf16-convert weights; build concatenated BqT.
// ============================================================
__global__ __launch_bounds__(256) void kPrep(
    const float* __restrict__ W_sum, const float* __restrict__ W_ab1,
    const float* __restrict__ W_er,  const float* __restrict__ W_ad,
    const float* __restrict__ key_mem, const float* __restrict__ W_df1,
    u16* __restrict__ WsumT, u16* __restrict__ Wab1T,
    u16* __restrict__ WerT,  u16* __restrict__ WaddT,
    u16* __restrict__ BqT)
{
  int e = blockIdx.x * 256 + threadIdx.x;
  if (e < 65536) {
    const int n = e >> 8, k = e & 255;
    WsumT[e] = f2bf(W_sum[k * 256 + n]);
  } else if (e < 131072) {
    e -= 65536;
    const int n = e >> 8, k = e & 255;
    Wab1T[e] = f2bf(W_ab1[k * 256 + n]);
  } else if (e < 147456) {
    e -= 131072;
    const int n = e >> 7, k = e & 127;
    WerT[e] = f2bf(W_er[k * 128 + n]);
  } else if (e < 163840) {
    e -= 147456;
    const int n = e >> 7, k = e & 127;
    WaddT[e] = f2bf(W_ad[k * 128 + n]);
  } else if (e < 184320) {
    e -= 163840;
    const int n = e >> 7, k = e & 127;
    BqT[e] = f2bf(n < 32 ? key_mem[n * 128 + k] : W_df1[k * 128 + (n - 32)]);
  }
}

// ============================================================
// kErAdd (FUSED): one block computes BOTH erase and add for its 128
// rows — A gathered ONCE (round-12 finding: y-split duplicated the
// gather). grid (BSN/128), block 256. LDS 48 KB -> 3 blocks/CU.
// ============================================================
__global__ __launch_bounds__(256) void kErAdd(
    const int* __restrict__ qa_data, const float* __restrict__ qa_table,
    const u16* __restrict__ WerT, const u16* __restrict__ WaddT,
    const float* __restrict__ b_er, const float* __restrict__ b_ad,
    u16* __restrict__ eras, u16* __restrict__ addb)
{
  __shared__ __align__(16) u16 As[4 * 128 * 32];   // [chunk][m][k'] 32 KB
  __shared__ __align__(16) u16 Bs[2 * 128 * 32];   // dbuf [n][k'] 16 KB
  const int tid = threadIdx.x;
  const int p0  = blockIdx.x * 128;

  // ---- stage A once: gather 128 rows of qa_table (f32 -> bf16)
  {
    const int r = tid >> 1, h = tid & 1;
    const long base = (long)qa_data[p0 + r] * DVN + h * 64;
    #pragma unroll
    for (int g = 0; g < 8; ++g) {
      const int k0 = h * 64 + g * 8;
      const float4 fa = *(const float4*)(qa_table + base + g * 8);
      const float4 fb = *(const float4*)(qa_table + base + g * 8 + 4);
      uint4 pk;
      pk.x = pack2(fa.x, fa.y); pk.y = pack2(fa.z, fa.w);
      pk.z = pack2(fb.x, fb.y); pk.w = pack2(fb.z, fb.w);
      *(uint4*)(As + (k0 >> 5) * 4096 + r * 32 + (k0 & 31)) = pk;
    }
  }

  const int lane = tid & 63, wave = tid >> 6;
  const int wr = (wave >> 1) * 64, wc = (wave & 1) * 64;
  const int c15 = lane & 15, q = lane >> 4;

  for (int sel = 0; sel < 2; ++sel) {
    const u16*   Wt = sel ? WaddT : WerT;
    const float* bb = sel ? b_ad  : b_er;
    u16*       outp = sel ? addb  : eras;

    // stage B chunk 0 into buf 0 (sel=0: also fences A staging via sync)
    {
      #pragma unroll
      for (int u = 0; u < 2; ++u) {
        const int f = tid + 256 * u;
        const int n = f >> 2, j = f & 3;
        *(uint4*)(Bs + n * 32 + j * 8) = *(const uint4*)(Wt + n * 128 + j * 8);
      }
    }
    __syncthreads();

    f32x4 acc[4][4];
    #pragma unroll
    for (int b = 0; b < 4; ++b) {
      const float bv = bb[wc + 16 * b + c15];
      #pragma unroll
      for (int a = 0; a < 4; ++a) acc[a][b] = (f32x4){bv, bv, bv, bv};
    }

    for (int c = 0; c < 4; ++c) {
      const int cur = c & 1;
      uint4 st[2];
      const bool more = (c + 1 < 4);
      if (more) {
        #pragma unroll
        for (int u = 0; u < 2; ++u) {
          const int f = tid + 256 * u;
          const int n = f >> 2, j = f & 3;
          st[u] = *(const uint4*)(Wt + n * 128 + (c + 1) * 32 + j * 8);
        }
      }
      bf16x8 af[4], bf[4];
      #pragma unroll
      for (int a = 0; a < 4; ++a)
        af[a] = *(const bf16x8*)(As + c * 4096 + (wr + 16 * a + c15) * 32 + q * 8);
      #pragma unroll
      for (int b = 0; b < 4; ++b)
        bf[b] = *(const bf16x8*)(Bs + cur * 4096 + (wc + 16 * b + c15) * 32 + q * 8);
      #pragma unroll
      for (int a = 0; a < 4; ++a)
        #pragma unroll
        for (int b = 0; b < 4; ++b)
          acc[a][b] = __builtin_amdgcn_mfma_f32_16x16x32_bf16(af[a], bf[b], acc[a][b], 0, 0, 0);
      if (more) {
        #pragma unroll
        for (int u = 0; u < 2; ++u) {
          const int f = tid + 256 * u;
          const int n = f >> 2, j = f & 3;
          *(uint4*)(Bs + (cur ^ 1) * 4096 + n * 32 + j * 8) = st[u];
        }
      }
      __syncthreads();   // tail sync also fences Bs for next sel's restage
    }

    // epilogue: activation + u16 stores (no LDS use)
    const int colb = wc + c15;
    #pragma unroll
    for (int a = 0; a < 4; ++a) {
      #pragma unroll
      for (int r = 0; r < 4; ++r) {
        const int row = p0 + wr + 16 * a + 4 * q + r;
        u16* yp = outp + (long)row * DVN + colb;
        #pragma unroll
        for (int b = 0; b < 4; ++b) {
          const float v = sel ? tanh_fast(acc[a][b][r]) : sigmoid_fast(acc[a][b][r]);
          yp[16 * b] = f2bf(v);
        }
      }
    }
  }
}

// ============================================================
// kQe (MFMA): one GEMM qe[128x128] @ BqT^T[128x160] per block.
// cols 0..31 -> softmax -> w_all; cols 32..159 -> diff head.
// (unchanged from round 12)
// ============================================================
__global__ __launch_bounds__(256) void kQe(
    const int* __restrict__ q_data, const float* __restrict__ q_table,
    const u16* __restrict__ BqT,
    const float* __restrict__ bdf1, const float* __restrict__ Wdf2,
    const float* __restrict__ bdf2,
    float* __restrict__ w_all, float* __restrict__ diff,
    u16* __restrict__ sin_buf)
{
  __shared__ __align__(16) u16 As[4 * 128 * 32];   // 32 KB
  __shared__ __align__(16) u16 Bs[4 * 160 * 32];   // 40 KB
  const int tid = threadIdx.x;
  const int p0  = blockIdx.x * 128;

  {
    const int r = tid >> 1, h = tid & 1;
    const long base = (long)q_data[p0 + r] * DKN + h * 64;
    #pragma unroll
    for (int g = 0; g < 8; ++g) {
      const int k0 = h * 64 + g * 8;
      const float4 fa = *(const float4*)(q_table + base + g * 8);
      const float4 fb = *(const float4*)(q_table + base + g * 8 + 4);
      uint4 pk;
      pk.x = pack2(fa.x, fa.y); pk.y = pack2(fa.z, fa.w);
      pk.z = pack2(fb.x, fb.y); pk.w = pack2(fb.z, fb.w);
      *(uint4*)(As + (k0 >> 5) * 4096 + r * 32 + (k0 & 31)) = pk;
      *(uint4*)(sin_buf + (long)(p0 + r) * DSN + DKN + k0) = pk;
    }
  }
  {
    #pragma unroll
    for (int u = 0; u < 10; ++u) {
      const int f = tid + 256 * u;
      const int n = f >> 4, jj = f & 15;
      *(uint4*)(Bs + (jj >> 2) * 5120 + n * 32 + (jj & 3) * 8) =
          *(const uint4*)(BqT + n * 128 + jj * 8);
    }
  }
  __syncthreads();

  const int lane = tid & 63, wave = tid >> 6;
  const int wr = (wave >> 1) * 64, wc = (wave & 1) * 80;
  const int c15 = lane & 15, q = lane >> 4;

  f32x4 acc[4][5];
  float w2v[5];
  #pragma unroll
  for (int b = 0; b < 5; ++b) {
    const int col = wc + 16 * b + c15;
    const float bv = (col < 32) ? 0.f : bdf1[col - 32];
    w2v[b] = (col < 32) ? 0.f : Wdf2[col - 32];
    #pragma unroll
    for (int a = 0; a < 4; ++a) acc[a][b] = (f32x4){bv, bv, bv, bv};
  }

  #pragma unroll
  for (int c = 0; c < 4; ++c) {
    bf16x8 af[4], bf[5];
    #pragma unroll
    for (int a = 0; a < 4; ++a)
      af[a] = *(const bf16x8*)(As + c * 4096 + (wr + 16 * a + c15) * 32 + q * 8);
    #pragma unroll
    for (int b = 0; b < 5; ++b)
      bf[b] = *(const bf16x8*)(Bs + c * 5120 + (wc + 16 * b + c15) * 32 + q * 8);
    #pragma unroll
    for (int a = 0; a < 4; ++a)
      #pragma unroll
      for (int b = 0; b < 5; ++b)
        acc[a][b] = __builtin_amdgcn_mfma_f32_16x16x32_bf16(af[a], bf[b], acc[a][b], 0, 0, 0);
  }

  if (wc == 0) {
    #pragma unroll
    for (int a = 0; a < 4; ++a) {
      #pragma unroll
      for (int r = 0; r < 4; ++r) {
        float s0 = acc[a][0][r], s1 = acc[a][1][r];
        float mx = fmaxf(s0, s1);
        mx = fmaxf(mx, __shfl_xor(mx, 1, 64));
        mx = fmaxf(mx, __shfl_xor(mx, 2, 64));
        mx = fmaxf(mx, __shfl_xor(mx, 4, 64));
        mx = fmaxf(mx, __shfl_xor(mx, 8, 64));
        const float e0 = __expf(s0 - mx), e1 = __expf(s1 - mx);
        float sm = e0 + e1;
        sm += __shfl_xor(sm, 1, 64);
        sm += __shfl_xor(sm, 2, 64);
        sm += __shfl_xor(sm, 4, 64);
        sm += __shfl_xor(sm, 8, 64);
        const float inv = 1.f / sm;
        const int row = p0 + wr + 16 * a + 4 * q + r;
        w_all[(long)row * MEMN + c15]      = e0 * inv;
        w_all[(long)row * MEMN + 16 + c15] = e1 * inv;
      }
    }
  }

  float sv[4][4];
  #pragma unroll
  for (int a = 0; a < 4; ++a) {
    #pragma unroll
    for (int r = 0; r < 4; ++r) {
      float s = 0.f;
      #pragma unroll
      for (int b = 0; b < 5; ++b)
        s = fmaf(tanh_fast(acc[a][b][r]), w2v[b], s);
      s += __shfl_xor(s, 1, 64);
      s += __shfl_xor(s, 2, 64);
      s += __shfl_xor(s, 4, 64);
      s += __shfl_xor(s, 8, 64);
      sv[a][r] = s;
    }
  }
  __syncthreads();
  float* red = (float*)As;
  if ((wave & 1) && c15 == 0) {
    #pragma unroll
    for (int a = 0; a < 4; ++a)
      #pragma unroll
      for (int r = 0; r < 4; ++r)
        red[wr + 16 * a + 4 * q + r] = sv[a][r];
  }
  __syncthreads();
  if (!(wave & 1) && c15 == 0) {
    const float bd = bdf2[0];
    #pragma unroll
    for (int a = 0; a < 4; ++a)
      #pragma unroll
      for (int r = 0; r < 4; ++r) {
        const int rr = wr + 16 * a + 4 * q + r;
        diff[p0 + rr] = sv[a][r] + red[rr] + bd;
      }
  }
}

// ============================================================
// kScan v6 (unchanged from round 12: deferred reduction, 78.6 µs)
// ============================================================
#define CHUNK_BYTES 12288
#define PB_OFF      25088     // 2*CHUNK_BYTES + 512

#define KSTAGE(K, BUF)                                                        \
  {                                                                           \
    const char* wsrc = (const char*)(w_all + (pbase + (long)(K) * 32) * MEMN);\
    const char* esrc = (const char*)(eras + (pbase + (long)(K) * 32) * DVN)   \
                       + ch * 128;                                            \
    const char* asrc = (const char*)(addb + (pbase + (long)(K) * 32) * DVN)   \
                       + ch * 128;                                            \
    char* dst = lds + (BUF) * CHUNK_BYTES;                                    \
    _Pragma("unroll")                                                         \
    for (int r = 0; r < 3; ++r) {                                             \
      const int o = (tid + r * 256) * 16;                                     \
      const char* src;                                                        \
      if (o < 4096) {                                                         \
        src = wsrc + o;                                                       \
      } else if (o < 8192) {                                                  \
        const int f = o - 4096;                                               \
        src = esrc + (f >> 7) * 256 + (f & 127);                              \
      } else {                                                                \
        const int f = o - 8192;                                               \
        src = asrc + (f >> 7) * 256 + (f & 127);                              \
      }                                                                       \
      GLOAD_LDS16(src, dst + o);                                              \
    }                                                                         \
  }

__global__ __launch_bounds__(256) void kScan(
    const float* __restrict__ w_all, const u16* __restrict__ eras,
    const u16* __restrict__ addb, const float* __restrict__ init_mem,
    u16* __restrict__ sin_buf)
{
  __shared__ __align__(16) char lds[PB_OFF + 32768];
  const int tid = threadIdx.x;
  const int ch  = blockIdx.x & 1;
  const int lc  = tid >> 2;
  const int gc  = ch * 64 + lc;
  const int h   = tid & 3;
  const long pbase = (long)(blockIdx.x >> 1) * S_N;

  float* pb = (float*)(lds + PB_OFF);

  float Mv[8];
  #pragma unroll
  for (int m = 0; m < 8; ++m) Mv[m] = init_mem[(h * 8 + m) * DVN + gc];

  const int lc2  = tid & 63;
  const int sblk = tid >> 6;
  u16* sp2 = sin_buf + pbase * DSN + ch * 64 + lc2;

  KSTAGE(0, 0)
  for (int k = 0; k < 16; ++k) {
    __syncthreads();
    if (k + 1 < 16) KSTAGE(k + 1, (k + 1) & 1)

    const char*  wb  = lds + (k & 1) * CHUNK_BYTES;
    const f32x4* wl4 = (const f32x4*)wb;
    const u16*   el  = (const u16*)(wb + 4096);
    const u16*   al  = (const u16*)(wb + 8192);

    f32x4 Wr[3][2];
    u16 er[3], ar[3];
    #pragma unroll
    for (int i = 0; i < 2; ++i) Wr[0][i] = wl4[h * 2 + i];
    er[0] = el[lc]; ar[0] = al[lc];
    #pragma unroll
    for (int i = 0; i < 2; ++i) Wr[1][i] = wl4[8 + h * 2 + i];
    er[1] = el[64 + lc]; ar[1] = al[64 + lc];

    #pragma unroll
    for (int s = 0; s < 32; ++s) {
      const int cur = s % 3, nx2 = (s + 2) % 3;
      Wr[nx2][0] = wl4[(s + 2) * 8 + h * 2];
      Wr[nx2][1] = wl4[(s + 2) * 8 + h * 2 + 1];
      er[nx2] = el[(s + 2) * 64 + lc];
      ar[nx2] = al[(s + 2) * 64 + lc];
      {
        float ac0 = 0.f, ac1 = 0.f, ac2 = 0.f, ac3 = 0.f;
        #pragma unroll
        for (int i = 0; i < 2; ++i) {
          ac0 = fmaf(Wr[cur][i][0], Mv[4 * i + 0], ac0);
          ac1 = fmaf(Wr[cur][i][1], Mv[4 * i + 1], ac1);
          ac2 = fmaf(Wr[cur][i][2], Mv[4 * i + 2], ac2);
          ac3 = fmaf(Wr[cur][i][3], Mv[4 * i + 3], ac3);
        }
        pb[s * 256 + lc * 4 + h] = (ac0 + ac1) + (ac2 + ac3);
        const float ec = bf2f(er[cur]);
        const float an = -bf2f(ar[cur]);
        #pragma unroll
        for (int i = 0; i < 2; ++i) {
          #pragma unroll
          for (int j = 0; j < 4; ++j) {
            const float t = fmaf(ec, Mv[4 * i + j], an);
            Mv[4 * i + j] = fmaf(-Wr[cur][i][j], t, Mv[4 * i + j]);
          }
        }
      }
    }

    __syncthreads();
    const int lb = k * 32;
    #pragma unroll
    for (int r = 0; r < 8; ++r) {
      const int s = sblk * 8 + r;
      const f32x4 pv = *(const f32x4*)(pb + s * 256 + lc2 * 4);
      sp2[(long)(lb + s) * DSN] = f2bf((pv[0] + pv[1]) + (pv[2] + pv[3]));
    }
  }
}

// ============================================================
// kSumAb (FUSED kSum+kAb+kOut): per 128-row block:
//  GEMM1: summary = tanh(X @ W_sum + b_sum)  [128x256], full cols,
//         acc[4][8] per wave (2x2 waves of 64 rows x 128 cols).
//  C->A: summary written (bf16) into As region (X dead) in the SAME
//         [chunk][row][32k] layout GEMM1 reads A from.
//  GEMM2: H = summary @ W_ab1 + b_ab1; ability = tanh(H) . W_ab2 + b_ab2
//  Final: read diff, compute pred/ability/difficulty/z, store f32 out.
// B single-buffered 16 KB w/ register prefetch. LDS 80 KB -> 2 blk/CU.
// ============================================================
__global__ __launch_bounds__(256) void kSumAb(
    const u16* __restrict__ X, const u16* __restrict__ WsumT,
    const float* __restrict__ bsum, const u16* __restrict__ Wab1T,
    const float* __restrict__ bab1, const float* __restrict__ Wab2,
    const float* __restrict__ bab2, const float* __restrict__ diffb,
    float* __restrict__ out)
{
  __shared__ __align__(16) u16 As[8 * 128 * 32];   // 64 KB: X, then summary
  __shared__ __align__(16) u16 Bs[256 * 32];       // 16 KB single-buffer B
  const int tid = threadIdx.x;
  const int p0  = blockIdx.x * 128;

  { // stage X [128][256] chunked
    #pragma unroll
    for (int u = 0; u < 16; ++u) {
      const int f = tid + 256 * u;
      const int r = f >> 5, j = f & 31;
      const uint4 raw = *(const uint4*)(X + (long)(p0 + r) * DSN + j * 8);
      *(uint4*)(As + (j >> 2) * 4096 + r * 32 + (j & 3) * 8) = raw;
    }
  }
  { // stage B chunk 0 (W_sum): 1024 uint4
    #pragma unroll
    for (int u = 0; u < 4; ++u) {
      const int f = tid + 256 * u;
      const int n = f >> 2, j = f & 3;
      *(uint4*)(Bs + n * 32 + j * 8) = *(const uint4*)(WsumT + n * 256 + j * 8);
    }
  }
  __syncthreads();

  const int lane = tid & 63, wave = tid >> 6;
  const int wr = (wave >> 1) * 64, wc = (wave & 1) * 128;
  const int c15 = lane & 15, q = lane >> 4;

  f32x4 acc[4][8];
  #pragma unroll
  for (int b = 0; b < 8; ++b) {
    const float bv = bsum[wc + 16 * b + c15];
    #pragma unroll
    for (int a = 0; a < 4; ++a) acc[a][b] = (f32x4){bv, bv, bv, bv};
  }

  // ---- GEMM1: X @ W_sum
  for (int c = 0; c < 8; ++c) {
    uint4 st[4];
    const bool more = (c + 1 < 8);
    if (more) {
      #pragma unroll
      for (int u = 0; u < 4; ++u) {
        const int f = tid + 256 * u;
        const int n = f >> 2, j = f & 3;
        st[u] = *(const uint4*)(WsumT + n * 256 + (c + 1) * 32 + j * 8);
      }
    }
    bf16x8 af[4], bf[8];
    #pragma unroll
    for (int a = 0; a < 4; ++a)
      af[a] = *(const bf16x8*)(As + c * 4096 + (wr + 16 * a + c15) * 32 + q * 8);
    #pragma unroll
    for (int b = 0; b < 8; ++b)
      bf[b] = *(const bf16x8*)(Bs + (wc + 16 * b + c15) * 32 + q * 8);
    #pragma unroll
    for (int a = 0; a < 4; ++a)
      #pragma unroll
      for (int b = 0; b < 8; ++b)
        acc[a][b] = __builtin_amdgcn_mfma_f32_16x16x32_bf16(af[a], bf[b], acc[a][b], 0, 0, 0);
    __syncthreads();                 // all Bs (and for c=7, As) reads done
    if (more) {
      #pragma unroll
      for (int u = 0; u < 4; ++u) {
        const int f = tid + 256 * u;
        const int n = f >> 2, j = f & 3;
        *(uint4*)(Bs + n * 32 + j * 8) = st[u];
      }
      __syncthreads();
    }
  }

  // ---- C->A round trip: summary (tanh) into As; stage W_ab1 chunk 0
  #pragma unroll
  for (int a = 0; a < 4; ++a)
    #pragma unroll
    for (int b = 0; b < 8; ++b) {
      const int col = wc + 16 * b + c15;
      u16* sp = As + (col >> 5) * 4096 + (col & 31);
      #pragma unroll
      for (int r = 0; r < 4; ++r) {
        const int row = wr + 16 * a + 4 * q + r;
        sp[row * 32] = f2bf(tanh_fast(acc[a][b][r]));
      }
    }
  {
    #pragma unroll
    for (int u = 0; u < 4; ++u) {
      const int f = tid + 256 * u;
      const int n = f >> 2, j = f & 3;
      *(uint4*)(Bs + n * 32 + j * 8) = *(const uint4*)(Wab1T + n * 256 + j * 8);
    }
  }
  __syncthreads();

  // ---- GEMM2: summary @ W_ab1
  float w2v[8];
  #pragma unroll
  for (int b = 0; b < 8; ++b) {
    const int col = wc + 16 * b + c15;
    const float bv = bab1[col];
    w2v[b] = Wab2[col];
    #pragma unroll
    for (int a = 0; a < 4; ++a) acc[a][b] = (f32x4){bv, bv, bv, bv};
  }
  for (int c = 0; c < 8; ++c) {
    uint4 st[4];
    const bool more = (c + 1 < 8);
    if (more) {
      #pragma unroll
      for (int u = 0; u < 4; ++u) {
        const int f = tid + 256 * u;
        const int n = f >> 2, j = f & 3;
        st[u] = *(const uint4*)(Wab1T + n * 256 + (c + 1) * 32 + j * 8);
      }
    }
    bf16x8 af[4], bf[8];
    #pragma unroll
    for (int a = 0; a < 4; ++a)
      af[a] = *(const bf16x8*)(As + c * 4096 + (wr + 16 * a + c15) * 32 + q * 8);
    #pragma unroll
    for (int b = 0; b < 8; ++b)
      bf[b] = *(const bf16x8*)(Bs + (wc + 16 * b + c15) * 32 + q * 8);
    #pragma unroll
    for (int a = 0; a < 4; ++a)
      #pragma unroll
      for (int b = 0; b < 8; ++b)
        acc[a][b] = __builtin_amdgcn_mfma_f32_16x16x32_bf16(af[a], bf[b], acc[a][b], 0, 0, 0);
    __syncthreads();
    if (more) {
      #pragma unroll
      for (int u = 0; u < 4; ++u) {
        const int f = tid + 256 * u;
        const int n = f >> 2, j = f & 3;
        *(uint4*)(Bs + n * 32 + j * 8) = st[u];
      }
      __syncthreads();
    }
  }

  // ---- epilogue: tanh + W_ab2 dot, reduce 16 col-lanes, pair waves,
  //      combine with diff, final outputs (absorbs kOut).
  float sv[4][4];
  #pragma unroll
  for (int a = 0; a < 4; ++a) {
    #pragma unroll
    for (int r = 0; r < 4; ++r) {
      float s = 0.f;
      #pragma unroll
      for (int b = 0; b < 8; ++b)
        s = fmaf(tanh_fast(acc[a][b][r]), w2v[b], s);
      s += __shfl_xor(s, 1, 64);
      s += __shfl_xor(s, 2, 64);
      s += __shfl_xor(s, 4, 64);
      s += __shfl_xor(s, 8, 64);
      sv[a][r] = s;
    }
  }
  float* red = (float*)Bs;   // 128 f32; Bs reads fenced by last GEMM2 sync
  if ((wave & 1) && c15 == 0) {
    #pragma unroll
    for (int a = 0; a < 4; ++a)
      #pragma unroll
      for (int r = 0; r < 4; ++r)
        red[wr + 16 * a + 4 * q + r] = sv[a][r];
  }
  __syncthreads();
  if (!(wave & 1) && c15 == 0) {
    const float bb = bab2[0];
    #pragma unroll
    for (int a = 0; a < 4; ++a)
      #pragma unroll
      for (int r = 0; r < 4; ++r) {
        const int rr = wr + 16 * a + 4 * q + r;
        const int p  = p0 + rr;
        const float ab = sv[a][r] + red[rr] + bb;
        const float d  = diffb[p];
        const float z  = 3.0f * ab - d;
        out[p]           = sigmoid_fast(z);
        out[BSN + p]     = ab;
        out[2 * BSN + p] = d;
        out[3 * BSN + p] = z;
      }
  }
}

// ============================================================
// launch
// ============================================================
extern "C" void kernel_launch(void* const* d_in, const int* in_sizes, int n_in,
                              void* d_out, int out_size, void* d_ws, size_t ws_size,
                              hipStream_t stream)
{
  const int*   q_data   = (const int*)d_in[0];
  const int*   qa_data  = (const int*)d_in[1];
  const float* q_table  = (const float*)d_in[2];
  const float* qa_table = (const float*)d_in[3];
  const float* key_mem  = (const float*)d_in[4];
  const float* init_mem = (const float*)d_in[5];
  const float* W_erase  = (const float*)d_in[6];
  const float* b_erase  = (const float*)d_in[7];
  const float* W_add    = (const float*)d_in[8];
  const float* b_add    = (const float*)d_in[9];
  const float* W_sum    = (const float*)d_in[10];
  const float* b_sum    = (const float*)d_in[11];
  const float* W_ab1    = (const float*)d_in[12];
  const float* b_ab1    = (const float*)d_in[13];
  const float* W_ab2    = (const float*)d_in[14];
  const float* b_ab2    = (const float*)d_in[15];
  const float* W_df1    = (const float*)d_in[16];
  const float* b_df1    = (const float*)d_in[17];
  const float* W_df2    = (const float*)d_in[18];
  const float* b_df2    = (const float*)d_in[19];

  // workspace layout (bytes); total 152,936,448
  char* ws = (char*)d_ws;
  float* w_all = (float*)(ws + 0);           // [BS][32] f32   16,777,216
  u16*   eras  = (u16*)(ws + 16777216);      // [BS][128] bf16 33,554,432
  u16*   addb  = (u16*)(ws + 50331648);      // [BS][128] bf16 33,554,432
  u16*   sinb  = (u16*)(ws + 83886080);      // [BS][256] bf16 67,108,864
  float* diffb = (float*)(ws + 150994944);   // [BS] f32          524,288
  u16*   WerT  = (u16*)(ws + 152567808);     // 32,768
  u16*   WaddT = (u16*)(ws + 152600576);     // 32,768
  u16*   WsumT = (u16*)(ws + 152633344);     // 131,072
  u16*   Wab1T = (u16*)(ws + 152764416);     // 131,072
  u16*   BqT   = (u16*)(ws + 152895488);     // 160x128 bf16 = 40,960

  kPrep<<<dim3(720), 256, 0, stream>>>(W_sum, W_ab1, W_erase, W_add, key_mem, W_df1,
                                       WsumT, Wab1T, WerT, WaddT, BqT);
  kErAdd<<<dim3(BSN / 128), 256, 0, stream>>>(qa_data, qa_table, WerT, WaddT,
                                              b_erase, b_add, eras, addb);
  kQe<<<dim3(BSN / 128), 256, 0, stream>>>(q_data, q_table, BqT, b_df1, W_df2, b_df2,
                                           w_all, diffb, sinb);
  kScan<<<dim3(B_N * 2), 256, 0, stream>>>(w_all, eras, addb, init_mem, sinb);
  kSumAb<<<dim3(BSN / 128), 256, 0, stream>>>(sinb, WsumT, b_sum, Wab1T, b_ab1,
                                              W_ab2, b_ab2, diffb, (float*)d_out);
}

// Round 14
// 355.029 us; speedup vs baseline: 1.6026x; 1.6026x over previous
//
#include <hip/hip_runtime.h>
#include <hip/hip_bf16.h>

typedef unsigned short u16;
typedef unsigned int   u32;

#define B_N   256
#define S_N   512
#define BSN   (B_N * S_N)      // 131072 positions
#define MEMN  32
#define DKN   128
#define DVN   128
#define DSN   256

typedef __attribute__((ext_vector_type(8))) short bf16x8;
typedef __attribute__((ext_vector_type(4))) float f32x4;

// ---------- helpers ----------
__device__ __forceinline__ float bf2f(u16 u) {
  union { u32 i; float f; } v; v.i = ((u32)u) << 16; return v.f;
}
__device__ __forceinline__ u16 f2bf(float f) {
  union { float f; u32 i; } v; v.f = f;
  u32 x = v.i;
  x += 0x7fffu + ((x >> 16) & 1u);   // RNE
  return (u16)(x >> 16);
}
__device__ __forceinline__ u32 pack2(float a, float b) {
  return (u32)f2bf(a) | ((u32)f2bf(b) << 16);
}
__device__ __forceinline__ float sigmoid_fast(float x) { return 1.f / (1.f + __expf(-x)); }
__device__ __forceinline__ float tanh_fast(float x)    { return 1.f - 2.f / (__expf(2.f * x) + 1.f); }

#define GLOAD_LDS16(g, l)                                         \
  __builtin_amdgcn_global_load_lds(                               \
      (const __attribute__((address_space(1))) void*)(g),         \
      (__attribute__((address_space(3))) void*)(l), 16, 0, 0)

// ============================================================
// kPrep: transpose + bf16-convert weights; build concatenated BqT.
// ============================================================
__global__ __launch_bounds__(256) void kPrep(
    const float* __restrict__ W_sum, const float* __restrict__ W_ab1,
    const float* __restrict__ W_er,  const float* __restrict__ W_ad,
    const float* __restrict__ key_mem, const float* __restrict__ W_df1,
    u16* __restrict__ WsumT, u16* __restrict__ Wab1T,
    u16* __restrict__ WerT,  u16* __restrict__ WaddT,
    u16* __restrict__ BqT)
{
  int e = blockIdx.x * 256 + threadIdx.x;
  if (e < 65536) {
    const int n = e >> 8, k = e & 255;
    WsumT[e] = f2bf(W_sum[k * 256 + n]);
  } else if (e < 131072) {
    e -= 65536;
    const int n = e >> 8, k = e & 255;
    Wab1T[e] = f2bf(W_ab1[k * 256 + n]);
  } else if (e < 147456) {
    e -= 131072;
    const int n = e >> 7, k = e & 127;
    WerT[e] = f2bf(W_er[k * 128 + n]);
  } else if (e < 163840) {
    e -= 147456;
    const int n = e >> 7, k = e & 127;
    WaddT[e] = f2bf(W_ad[k * 128 + n]);
  } else if (e < 184320) {
    e -= 163840;
    const int n = e >> 7, k = e & 127;
    BqT[e] = f2bf(n < 32 ? key_mem[n * 128 + k] : W_df1[k * 128 + (n - 32)]);
  }
}

// ============================================================
// kErAdd (FUSED, kept from round 13): one block computes BOTH erase
// and add for its 128 rows — A gathered ONCE.
// grid (BSN/128), block 256. LDS 48 KB -> 3 blocks/CU.
// ============================================================
__global__ __launch_bounds__(256) void kErAdd(
    const int* __restrict__ qa_data, const float* __restrict__ qa_table,
    const u16* __restrict__ WerT, const u16* __restrict__ WaddT,
    const float* __restrict__ b_er, const float* __restrict__ b_ad,
    u16* __restrict__ eras, u16* __restrict__ addb)
{
  __shared__ __align__(16) u16 As[4 * 128 * 32];   // [chunk][m][k'] 32 KB
  __shared__ __align__(16) u16 Bs[2 * 128 * 32];   // dbuf [n][k'] 16 KB
  const int tid = threadIdx.x;
  const int p0  = blockIdx.x * 128;

  // ---- stage A once: gather 128 rows of qa_table (f32 -> bf16)
  {
    const int r = tid >> 1, h = tid & 1;
    const long base = (long)qa_data[p0 + r] * DVN + h * 64;
    #pragma unroll
    for (int g = 0; g < 8; ++g) {
      const int k0 = h * 64 + g * 8;
      const float4 fa = *(const float4*)(qa_table + base + g * 8);
      const float4 fb = *(const float4*)(qa_table + base + g * 8 + 4);
      uint4 pk;
      pk.x = pack2(fa.x, fa.y); pk.y = pack2(fa.z, fa.w);
      pk.z = pack2(fb.x, fb.y); pk.w = pack2(fb.z, fb.w);
      *(uint4*)(As + (k0 >> 5) * 4096 + r * 32 + (k0 & 31)) = pk;
    }
  }

  const int lane = tid & 63, wave = tid >> 6;
  const int wr = (wave >> 1) * 64, wc = (wave & 1) * 64;
  const int c15 = lane & 15, q = lane >> 4;

  for (int sel = 0; sel < 2; ++sel) {
    const u16*   Wt = sel ? WaddT : WerT;
    const float* bb = sel ? b_ad  : b_er;
    u16*       outp = sel ? addb  : eras;

    {
      #pragma unroll
      for (int u = 0; u < 2; ++u) {
        const int f = tid + 256 * u;
        const int n = f >> 2, j = f & 3;
        *(uint4*)(Bs + n * 32 + j * 8) = *(const uint4*)(Wt + n * 128 + j * 8);
      }
    }
    __syncthreads();

    f32x4 acc[4][4];
    #pragma unroll
    for (int b = 0; b < 4; ++b) {
      const float bv = bb[wc + 16 * b + c15];
      #pragma unroll
      for (int a = 0; a < 4; ++a) acc[a][b] = (f32x4){bv, bv, bv, bv};
    }

    for (int c = 0; c < 4; ++c) {
      const int cur = c & 1;
      uint4 st[2];
      const bool more = (c + 1 < 4);
      if (more) {
        #pragma unroll
        for (int u = 0; u < 2; ++u) {
          const int f = tid + 256 * u;
          const int n = f >> 2, j = f & 3;
          st[u] = *(const uint4*)(Wt + n * 128 + (c + 1) * 32 + j * 8);
        }
      }
      bf16x8 af[4], bf[4];
      #pragma unroll
      for (int a = 0; a < 4; ++a)
        af[a] = *(const bf16x8*)(As + c * 4096 + (wr + 16 * a + c15) * 32 + q * 8);
      #pragma unroll
      for (int b = 0; b < 4; ++b)
        bf[b] = *(const bf16x8*)(Bs + cur * 4096 + (wc + 16 * b + c15) * 32 + q * 8);
      #pragma unroll
      for (int a = 0; a < 4; ++a)
        #pragma unroll
        for (int b = 0; b < 4; ++b)
          acc[a][b] = __builtin_amdgcn_mfma_f32_16x16x32_bf16(af[a], bf[b], acc[a][b], 0, 0, 0);
      if (more) {
        #pragma unroll
        for (int u = 0; u < 2; ++u) {
          const int f = tid + 256 * u;
          const int n = f >> 2, j = f & 3;
          *(uint4*)(Bs + (cur ^ 1) * 4096 + n * 32 + j * 8) = st[u];
        }
      }
      __syncthreads();   // tail sync also fences Bs for next sel's restage
    }

    const int colb = wc + c15;
    #pragma unroll
    for (int a = 0; a < 4; ++a) {
      #pragma unroll
      for (int r = 0; r < 4; ++r) {
        const int row = p0 + wr + 16 * a + 4 * q + r;
        u16* yp = outp + (long)row * DVN + colb;
        #pragma unroll
        for (int b = 0; b < 4; ++b) {
          const float v = sel ? tanh_fast(acc[a][b][r]) : sigmoid_fast(acc[a][b][r]);
          yp[16 * b] = f2bf(v);
        }
      }
    }
  }
}

// ============================================================
// kQe (MFMA): qe[128x128] @ BqT^T[128x160]; softmax + diff head.
// (unchanged)
// ============================================================
__global__ __launch_bounds__(256) void kQe(
    const int* __restrict__ q_data, const float* __restrict__ q_table,
    const u16* __restrict__ BqT,
    const float* __restrict__ bdf1, const float* __restrict__ Wdf2,
    const float* __restrict__ bdf2,
    float* __restrict__ w_all, float* __restrict__ diff,
    u16* __restrict__ sin_buf)
{
  __shared__ __align__(16) u16 As[4 * 128 * 32];   // 32 KB
  __shared__ __align__(16) u16 Bs[4 * 160 * 32];   // 40 KB
  const int tid = threadIdx.x;
  const int p0  = blockIdx.x * 128;

  {
    const int r = tid >> 1, h = tid & 1;
    const long base = (long)q_data[p0 + r] * DKN + h * 64;
    #pragma unroll
    for (int g = 0; g < 8; ++g) {
      const int k0 = h * 64 + g * 8;
      const float4 fa = *(const float4*)(q_table + base + g * 8);
      const float4 fb = *(const float4*)(q_table + base + g * 8 + 4);
      uint4 pk;
      pk.x = pack2(fa.x, fa.y); pk.y = pack2(fa.z, fa.w);
      pk.z = pack2(fb.x, fb.y); pk.w = pack2(fb.z, fb.w);
      *(uint4*)(As + (k0 >> 5) * 4096 + r * 32 + (k0 & 31)) = pk;
      *(uint4*)(sin_buf + (long)(p0 + r) * DSN + DKN + k0) = pk;
    }
  }
  {
    #pragma unroll
    for (int u = 0; u < 10; ++u) {
      const int f = tid + 256 * u;
      const int n = f >> 4, jj = f & 15;
      *(uint4*)(Bs + (jj >> 2) * 5120 + n * 32 + (jj & 3) * 8) =
          *(const uint4*)(BqT + n * 128 + jj * 8);
    }
  }
  __syncthreads();

  const int lane = tid & 63, wave = tid >> 6;
  const int wr = (wave >> 1) * 64, wc = (wave & 1) * 80;
  const int c15 = lane & 15, q = lane >> 4;

  f32x4 acc[4][5];
  float w2v[5];
  #pragma unroll
  for (int b = 0; b < 5; ++b) {
    const int col = wc + 16 * b + c15;
    const float bv = (col < 32) ? 0.f : bdf1[col - 32];
    w2v[b] = (col < 32) ? 0.f : Wdf2[col - 32];
    #pragma unroll
    for (int a = 0; a < 4; ++a) acc[a][b] = (f32x4){bv, bv, bv, bv};
  }

  #pragma unroll
  for (int c = 0; c < 4; ++c) {
    bf16x8 af[4], bf[5];
    #pragma unroll
    for (int a = 0; a < 4; ++a)
      af[a] = *(const bf16x8*)(As + c * 4096 + (wr + 16 * a + c15) * 32 + q * 8);
    #pragma unroll
    for (int b = 0; b < 5; ++b)
      bf[b] = *(const bf16x8*)(Bs + c * 5120 + (wc + 16 * b + c15) * 32 + q * 8);
    #pragma unroll
    for (int a = 0; a < 4; ++a)
      #pragma unroll
      for (int b = 0; b < 5; ++b)
        acc[a][b] = __builtin_amdgcn_mfma_f32_16x16x32_bf16(af[a], bf[b], acc[a][b], 0, 0, 0);
  }

  if (wc == 0) {
    #pragma unroll
    for (int a = 0; a < 4; ++a) {
      #pragma unroll
      for (int r = 0; r < 4; ++r) {
        float s0 = acc[a][0][r], s1 = acc[a][1][r];
        float mx = fmaxf(s0, s1);
        mx = fmaxf(mx, __shfl_xor(mx, 1, 64));
        mx = fmaxf(mx, __shfl_xor(mx, 2, 64));
        mx = fmaxf(mx, __shfl_xor(mx, 4, 64));
        mx = fmaxf(mx, __shfl_xor(mx, 8, 64));
        const float e0 = __expf(s0 - mx), e1 = __expf(s1 - mx);
        float sm = e0 + e1;
        sm += __shfl_xor(sm, 1, 64);
        sm += __shfl_xor(sm, 2, 64);
        sm += __shfl_xor(sm, 4, 64);
        sm += __shfl_xor(sm, 8, 64);
        const float inv = 1.f / sm;
        const int row = p0 + wr + 16 * a + 4 * q + r;
        w_all[(long)row * MEMN + c15]      = e0 * inv;
        w_all[(long)row * MEMN + 16 + c15] = e1 * inv;
      }
    }
  }

  float sv[4][4];
  #pragma unroll
  for (int a = 0; a < 4; ++a) {
    #pragma unroll
    for (int r = 0; r < 4; ++r) {
      float s = 0.f;
      #pragma unroll
      for (int b = 0; b < 5; ++b)
        s = fmaf(tanh_fast(acc[a][b][r]), w2v[b], s);
      s += __shfl_xor(s, 1, 64);
      s += __shfl_xor(s, 2, 64);
      s += __shfl_xor(s, 4, 64);
      s += __shfl_xor(s, 8, 64);
      sv[a][r] = s;
    }
  }
  __syncthreads();
  float* red = (float*)As;
  if ((wave & 1) && c15 == 0) {
    #pragma unroll
    for (int a = 0; a < 4; ++a)
      #pragma unroll
      for (int r = 0; r < 4; ++r)
        red[wr + 16 * a + 4 * q + r] = sv[a][r];
  }
  __syncthreads();
  if (!(wave & 1) && c15 == 0) {
    const float bd = bdf2[0];
    #pragma unroll
    for (int a = 0; a < 4; ++a)
      #pragma unroll
      for (int r = 0; r < 4; ++r) {
        const int rr = wr + 16 * a + 4 * q + r;
        diff[p0 + rr] = sv[a][r] + red[rr] + bd;
      }
  }
}

// ============================================================
// kScan v6 (unchanged from round 12: deferred reduction, 78.6 µs)
// ============================================================
#define CHUNK_BYTES 12288
#define PB_OFF      25088     // 2*CHUNK_BYTES + 512

#define KSTAGE(K, BUF)                                                        \
  {                                                                           \
    const char* wsrc = (const char*)(w_all + (pbase + (long)(K) * 32) * MEMN);\
    const char* esrc = (const char*)(eras + (pbase + (long)(K) * 32) * DVN)   \
                       + ch * 128;                                            \
    const char* asrc = (const char*)(addb + (pbase + (long)(K) * 32) * DVN)   \
                       + ch * 128;                                            \
    char* dst = lds + (BUF) * CHUNK_BYTES;                                    \
    _Pragma("unroll")                                                         \
    for (int r = 0; r < 3; ++r) {                                             \
      const int o = (tid + r * 256) * 16;                                     \
      const char* src;                                                        \
      if (o < 4096) {                                                         \
        src = wsrc + o;                                                       \
      } else if (o < 8192) {                                                  \
        const int f = o - 4096;                                               \
        src = esrc + (f >> 7) * 256 + (f & 127);                              \
      } else {                                                                \
        const int f = o - 8192;                                               \
        src = asrc + (f >> 7) * 256 + (f & 127);                              \
      }                                                                       \
      GLOAD_LDS16(src, dst + o);                                              \
    }                                                                         \
  }

__global__ __launch_bounds__(256) void kScan(
    const float* __restrict__ w_all, const u16* __restrict__ eras,
    const u16* __restrict__ addb, const float* __restrict__ init_mem,
    u16* __restrict__ sin_buf)
{
  __shared__ __align__(16) char lds[PB_OFF + 32768];
  const int tid = threadIdx.x;
  const int ch  = blockIdx.x & 1;
  const int lc  = tid >> 2;
  const int gc  = ch * 64 + lc;
  const int h   = tid & 3;
  const long pbase = (long)(blockIdx.x >> 1) * S_N;

  float* pb = (float*)(lds + PB_OFF);

  float Mv[8];
  #pragma unroll
  for (int m = 0; m < 8; ++m) Mv[m] = init_mem[(h * 8 + m) * DVN + gc];

  const int lc2  = tid & 63;
  const int sblk = tid >> 6;
  u16* sp2 = sin_buf + pbase * DSN + ch * 64 + lc2;

  KSTAGE(0, 0)
  for (int k = 0; k < 16; ++k) {
    __syncthreads();
    if (k + 1 < 16) KSTAGE(k + 1, (k + 1) & 1)

    const char*  wb  = lds + (k & 1) * CHUNK_BYTES;
    const f32x4* wl4 = (const f32x4*)wb;
    const u16*   el  = (const u16*)(wb + 4096);
    const u16*   al  = (const u16*)(wb + 8192);

    f32x4 Wr[3][2];
    u16 er[3], ar[3];
    #pragma unroll
    for (int i = 0; i < 2; ++i) Wr[0][i] = wl4[h * 2 + i];
    er[0] = el[lc]; ar[0] = al[lc];
    #pragma unroll
    for (int i = 0; i < 2; ++i) Wr[1][i] = wl4[8 + h * 2 + i];
    er[1] = el[64 + lc]; ar[1] = al[64 + lc];

    #pragma unroll
    for (int s = 0; s < 32; ++s) {
      const int cur = s % 3, nx2 = (s + 2) % 3;
      Wr[nx2][0] = wl4[(s + 2) * 8 + h * 2];
      Wr[nx2][1] = wl4[(s + 2) * 8 + h * 2 + 1];
      er[nx2] = el[(s + 2) * 64 + lc];
      ar[nx2] = al[(s + 2) * 64 + lc];
      {
        float ac0 = 0.f, ac1 = 0.f, ac2 = 0.f, ac3 = 0.f;
        #pragma unroll
        for (int i = 0; i < 2; ++i) {
          ac0 = fmaf(Wr[cur][i][0], Mv[4 * i + 0], ac0);
          ac1 = fmaf(Wr[cur][i][1], Mv[4 * i + 1], ac1);
          ac2 = fmaf(Wr[cur][i][2], Mv[4 * i + 2], ac2);
          ac3 = fmaf(Wr[cur][i][3], Mv[4 * i + 3], ac3);
        }
        pb[s * 256 + lc * 4 + h] = (ac0 + ac1) + (ac2 + ac3);
        const float ec = bf2f(er[cur]);
        const float an = -bf2f(ar[cur]);
        #pragma unroll
        for (int i = 0; i < 2; ++i) {
          #pragma unroll
          for (int j = 0; j < 4; ++j) {
            const float t = fmaf(ec, Mv[4 * i + j], an);
            Mv[4 * i + j] = fmaf(-Wr[cur][i][j], t, Mv[4 * i + j]);
          }
        }
      }
    }

    __syncthreads();
    const int lb = k * 32;
    #pragma unroll
    for (int r = 0; r < 8; ++r) {
      const int s = sblk * 8 + r;
      const f32x4 pv = *(const f32x4*)(pb + s * 256 + lc2 * 4);
      sp2[(long)(lb + s) * DSN] = f2bf((pv[0] + pv[1]) + (pv[2] + pv[3]));
    }
  }
}

// ============================================================
// kSum (round-12 version): summary = tanh(sin @ W_sum + b). K=256.
// grid (BSN/128, 2: col half). LDS: A 64KB + B 16KB = 80KB.
// ============================================================
__global__ __launch_bounds__(256) void kSum(
    const u16* __restrict__ X, const u16* __restrict__ WsumT,
    const float* __restrict__ bias, u16* __restrict__ Y)
{
  __shared__ __align__(16) u16 As[8 * 128 * 32];   // 64 KB
  __shared__ __align__(16) u16 Bs[2 * 128 * 32];   // 16 KB
  const int tid = threadIdx.x;
  const int p0  = blockIdx.x * 128;
  const int j0  = blockIdx.y * 128;

  {
    #pragma unroll
    for (int u = 0; u < 16; ++u) {
      const int f = tid + 256 * u;
      const int r = f >> 5, j = f & 31;
      const uint4 raw = *(const uint4*)(X + (long)(p0 + r) * DSN + j * 8);
      *(uint4*)(As + (j >> 2) * 4096 + r * 32 + (j & 3) * 8) = raw;
    }
  }
  {
    #pragma unroll
    for (int u = 0; u < 2; ++u) {
      const int f = tid + 256 * u;
      const int n = f >> 2, j = f & 3;
      *(uint4*)(Bs + n * 32 + j * 8) = *(const uint4*)(WsumT + (j0 + n) * 256 + j * 8);
    }
  }
  __syncthreads();

  const int lane = tid & 63, wave = tid >> 6;
  const int wr = (wave >> 1) * 64, wc = (wave & 1) * 64;
  const int c15 = lane & 15, q = lane >> 4;

  f32x4 acc[4][4];
  #pragma unroll
  for (int b = 0; b < 4; ++b) {
    const float bv = bias[j0 + wc + 16 * b + c15];
    #pragma unroll
    for (int a = 0; a < 4; ++a) acc[a][b] = (f32x4){bv, bv, bv, bv};
  }

  for (int c = 0; c < 8; ++c) {
    const int cur = c & 1;
    uint4 st[2];
    const bool more = (c + 1 < 8);
    if (more) {
      #pragma unroll
      for (int u = 0; u < 2; ++u) {
        const int f = tid + 256 * u;
        const int n = f >> 2, j = f & 3;
        st[u] = *(const uint4*)(WsumT + (j0 + n) * 256 + (c + 1) * 32 + j * 8);
      }
    }
    bf16x8 af[4], bf[4];
    #pragma unroll
    for (int a = 0; a < 4; ++a)
      af[a] = *(const bf16x8*)(As + c * 4096 + (wr + 16 * a + c15) * 32 + q * 8);
    #pragma unroll
    for (int b = 0; b < 4; ++b)
      bf[b] = *(const bf16x8*)(Bs + cur * 4096 + (wc + 16 * b + c15) * 32 + q * 8);
    #pragma unroll
    for (int a = 0; a < 4; ++a)
      #pragma unroll
      for (int b = 0; b < 4; ++b)
        acc[a][b] = __builtin_amdgcn_mfma_f32_16x16x32_bf16(af[a], bf[b], acc[a][b], 0, 0, 0);
    if (more) {
      #pragma unroll
      for (int u = 0; u < 2; ++u) {
        const int f = tid + 256 * u;
        const int n = f >> 2, j = f & 3;
        *(uint4*)(Bs + (cur ^ 1) * 4096 + n * 32 + j * 8) = st[u];
      }
    }
    __syncthreads();
  }

  const int colb = j0 + wc + c15;
  #pragma unroll
  for (int a = 0; a < 4; ++a) {
    #pragma unroll
    for (int r = 0; r < 4; ++r) {
      const int row = p0 + wr + 16 * a + 4 * q + r;
      u16* yp = Y + (long)row * DSN + colb;
      #pragma unroll
      for (int b = 0; b < 4; ++b)
        yp[16 * b] = f2bf(tanh_fast(acc[a][b][r]));
    }
  }
}

// ============================================================
// kAb (round-12 version): MFMA GEMM + fused W_ab2 dot.
// ============================================================
__global__ __launch_bounds__(256) void kAb(
    const u16* __restrict__ X, const u16* __restrict__ Wab1T,
    const float* __restrict__ bias, const float* __restrict__ Wab2,
    float* __restrict__ part)
{
  __shared__ __align__(16) u16 As[8 * 128 * 32];
  __shared__ __align__(16) u16 Bs[2 * 128 * 32];
  const int tid = threadIdx.x;
  const int p0  = blockIdx.x * 128;
  const int j0  = blockIdx.y * 128;

  {
    #pragma unroll
    for (int u = 0; u < 16; ++u) {
      const int f = tid + 256 * u;
      const int r = f >> 5, j = f & 31;
      const uint4 raw = *(const uint4*)(X + (long)(p0 + r) * DSN + j * 8);
      *(uint4*)(As + (j >> 2) * 4096 + r * 32 + (j & 3) * 8) = raw;
    }
  }
  {
    #pragma unroll
    for (int u = 0; u < 2; ++u) {
      const int f = tid + 256 * u;
      const int n = f >> 2, j = f & 3;
      *(uint4*)(Bs + n * 32 + j * 8) = *(const uint4*)(Wab1T + (j0 + n) * 256 + j * 8);
    }
  }
  __syncthreads();

  const int lane = tid & 63, wave = tid >> 6;
  const int wr = (wave >> 1) * 64, wc = (wave & 1) * 64;
  const int c15 = lane & 15, q = lane >> 4;

  f32x4 acc[4][4];
  float w2v[4];
  #pragma unroll
  for (int b = 0; b < 4; ++b) {
    const int col = j0 + wc + 16 * b + c15;
    const float bv = bias[col];
    w2v[b] = Wab2[col];
    #pragma unroll
    for (int a = 0; a < 4; ++a) acc[a][b] = (f32x4){bv, bv, bv, bv};
  }

  for (int c = 0; c < 8; ++c) {
    const int cur = c & 1;
    uint4 st[2];
    const bool more = (c + 1 < 8);
    if (more) {
      #pragma unroll
      for (int u = 0; u < 2; ++u) {
        const int f = tid + 256 * u;
        const int n = f >> 2, j = f & 3;
        st[u] = *(const uint4*)(Wab1T + (j0 + n) * 256 + (c + 1) * 32 + j * 8);
      }
    }
    bf16x8 af[4], bf[4];
    #pragma unroll
    for (int a = 0; a < 4; ++a)
      af[a] = *(const bf16x8*)(As + c * 4096 + (wr + 16 * a + c15) * 32 + q * 8);
    #pragma unroll
    for (int b = 0; b < 4; ++b)
      bf[b] = *(const bf16x8*)(Bs + cur * 4096 + (wc + 16 * b + c15) * 32 + q * 8);
    #pragma unroll
    for (int a = 0; a < 4; ++a)
      #pragma unroll
      for (int b = 0; b < 4; ++b)
        acc[a][b] = __builtin_amdgcn_mfma_f32_16x16x32_bf16(af[a], bf[b], acc[a][b], 0, 0, 0);
    if (more) {
      #pragma unroll
      for (int u = 0; u < 2; ++u) {
        const int f = tid + 256 * u;
        const int n = f >> 2, j = f & 3;
        *(uint4*)(Bs + (cur ^ 1) * 4096 + n * 32 + j * 8) = st[u];
      }
    }
    __syncthreads();   // final barrier also fences Bs reuse below
  }

  float sv[4][4];
  #pragma unroll
  for (int a = 0; a < 4; ++a) {
    #pragma unroll
    for (int r = 0; r < 4; ++r) {
      float s = 0.f;
      #pragma unroll
      for (int b = 0; b < 4; ++b)
        s = fmaf(tanh_fast(acc[a][b][r]), w2v[b], s);
      s += __shfl_xor(s, 1, 64);
      s += __shfl_xor(s, 2, 64);
      s += __shfl_xor(s, 4, 64);
      s += __shfl_xor(s, 8, 64);
      sv[a][r] = s;
    }
  }
  float* red = (float*)Bs;
  if ((wave & 1) && c15 == 0) {
    #pragma unroll
    for (int a = 0; a < 4; ++a)
      #pragma unroll
      for (int r = 0; r < 4; ++r)
        red[wr + 16 * a + 4 * q + r] = sv[a][r];
  }
  __syncthreads();
  if (!(wave & 1) && c15 == 0) {
    #pragma unroll
    for (int a = 0; a < 4; ++a)
      #pragma unroll
      for (int r = 0; r < 4; ++r) {
        const int rr = wr + 16 * a + 4 * q + r;
        part[(long)blockIdx.y * BSN + p0 + rr] = sv[a][r] + red[rr];
      }
  }
}

// ============================================================
// kOut: combine. grid (BSN/256), block 256. f32 output.
// ============================================================
__global__ __launch_bounds__(256) void kOut(
    const float* __restrict__ part, const float* __restrict__ diff,
    const float* __restrict__ bab2, float* __restrict__ out)
{
  const int p = blockIdx.x * 256 + threadIdx.x;
  const float ab = part[p] + part[BSN + p] + bab2[0];
  const float d  = diff[p];
  const float z  = 3.0f * ab - d;
  out[p]           = sigmoid_fast(z);
  out[BSN + p]     = ab;
  out[2 * BSN + p] = d;
  out[3 * BSN + p] = z;
}

// ============================================================
// launch
// ============================================================
extern "C" void kernel_launch(void* const* d_in, const int* in_sizes, int n_in,
                              void* d_out, int out_size, void* d_ws, size_t ws_size,
                              hipStream_t stream)
{
  const int*   q_data   = (const int*)d_in[0];
  const int*   qa_data  = (const int*)d_in[1];
  const float* q_table  = (const float*)d_in[2];
  const float* qa_table = (const float*)d_in[3];
  const float* key_mem  = (const float*)d_in[4];
  const float* init_mem = (const float*)d_in[5];
  const float* W_erase  = (const float*)d_in[6];
  const float* b_erase  = (const float*)d_in[7];
  const float* W_add    = (const float*)d_in[8];
  const float* b_add    = (const float*)d_in[9];
  const float* W_sum    = (const float*)d_in[10];
  const float* b_sum    = (const float*)d_in[11];
  const float* W_ab1    = (const float*)d_in[12];
  const float* b_ab1    = (const float*)d_in[13];
  const float* W_ab2    = (const float*)d_in[14];
  const float* b_ab2    = (const float*)d_in[15];
  const float* W_df1    = (const float*)d_in[16];
  const float* b_df1    = (const float*)d_in[17];
  const float* W_df2    = (const float*)d_in[18];
  const float* b_df2    = (const float*)d_in[19];

  // workspace layout (bytes); total 152,936,448
  char* ws = (char*)d_ws;
  float* w_all = (float*)(ws + 0);           // [BS][32] f32   16,777,216
  u16*   eras  = (u16*)(ws + 16777216);      // [BS][128] bf16 33,554,432
  u16*   addb  = (u16*)(ws + 50331648);      // [BS][128] bf16 33,554,432
  u16*   sinb  = (u16*)(ws + 83886080);      // [BS][256] bf16 67,108,864
  float* diffb = (float*)(ws + 150994944);   // [BS] f32          524,288
  float* part  = (float*)(ws + 151519232);   // [2][BS] f32     1,048,576
  u16*   WerT  = (u16*)(ws + 152567808);     // 32,768
  u16*   WaddT = (u16*)(ws + 152600576);     // 32,768
  u16*   WsumT = (u16*)(ws + 152633344);     // 131,072
  u16*   Wab1T = (u16*)(ws + 152764416);     // 131,072
  u16*   BqT   = (u16*)(ws + 152895488);     // 160x128 bf16 = 40,960
  u16*   summ  = eras;                       // summary reuses eras+addb

  kPrep<<<dim3(720), 256, 0, stream>>>(W_sum, W_ab1, W_erase, W_add, key_mem, W_df1,
                                       WsumT, Wab1T, WerT, WaddT, BqT);
  kErAdd<<<dim3(BSN / 128), 256, 0, stream>>>(qa_data, qa_table, WerT, WaddT,
                                              b_erase, b_add, eras, addb);
  kQe<<<dim3(BSN / 128), 256, 0, stream>>>(q_data, q_table, BqT, b_df1, W_df2, b_df2,
                                           w_all, diffb, sinb);
  kScan<<<dim3(B_N * 2), 256, 0, stream>>>(w_all, eras, addb, init_mem, sinb);
  kSum<<<dim3(BSN / 128, 2), 256, 0, stream>>>(sinb, WsumT, b_sum, summ);
  kAb<<<dim3(BSN / 128, 2), 256, 0, stream>>>(summ, Wab1T, b_ab1, W_ab2, part);
  kOut<<<dim3(BSN / 256), 256, 0, stream>>>(part, diffb, b_ab2, (float*)d_out);
}

// Round 15
// 327.150 us; speedup vs baseline: 1.7391x; 1.0852x over previous
//
#include <hip/hip_runtime.h>
#include <hip/hip_bf16.h>

typedef unsigned short u16;
typedef unsigned int   u32;

#define B_N   256
#define S_N   512
#define BSN   (B_N * S_N)      // 131072 positions
#define MEMN  32
#define DKN   128
#define DVN   128
#define DSN   256

typedef __attribute__((ext_vector_type(8))) short bf16x8;
typedef __attribute__((ext_vector_type(4))) float f32x4;

// ---------- helpers ----------
__device__ __forceinline__ float bf2f(u16 u) {
  union { u32 i; float f; } v; v.i = ((u32)u) << 16; return v.f;
}
__device__ __forceinline__ u16 f2bf(float f) {
  union { float f; u32 i; } v; v.f = f;
  u32 x = v.i;
  x += 0x7fffu + ((x >> 16) & 1u);   // RNE
  return (u16)(x >> 16);
}
__device__ __forceinline__ u32 pack2(float a, float b) {
  return (u32)f2bf(a) | ((u32)f2bf(b) << 16);
}
__device__ __forceinline__ float sigmoid_fast(float x) { return 1.f / (1.f + __expf(-x)); }
__device__ __forceinline__ float tanh_fast(float x)    { return 1.f - 2.f / (__expf(2.f * x) + 1.f); }

#define GLOAD_LDS16(g, l)                                         \
  __builtin_amdgcn_global_load_lds(                               \
      (const __attribute__((address_space(1))) void*)(g),         \
      (__attribute__((address_space(3))) void*)(l), 16, 0, 0)

// ============================================================
// kPrep: transpose + bf16-convert weights; build concatenated BqT.
// ============================================================
__global__ __launch_bounds__(256) void kPrep(
    const float* __restrict__ W_sum, const float* __restrict__ W_ab1,
    const float* __restrict__ W_er,  const float* __restrict__ W_ad,
    const float* __restrict__ key_mem, const float* __restrict__ W_df1,
    u16* __restrict__ WsumT, u16* __restrict__ Wab1T,
    u16* __restrict__ WerT,  u16* __restrict__ WaddT,
    u16* __restrict__ BqT)
{
  int e = blockIdx.x * 256 + threadIdx.x;
  if (e < 65536) {
    const int n = e >> 8, k = e & 255;
    WsumT[e] = f2bf(W_sum[k * 256 + n]);
  } else if (e < 131072) {
    e -= 65536;
    const int n = e >> 8, k = e & 255;
    Wab1T[e] = f2bf(W_ab1[k * 256 + n]);
  } else if (e < 147456) {
    e -= 131072;
    const int n = e >> 7, k = e & 127;
    WerT[e] = f2bf(W_er[k * 128 + n]);
  } else if (e < 163840) {
    e -= 147456;
    const int n = e >> 7, k = e & 127;
    WaddT[e] = f2bf(W_ad[k * 128 + n]);
  } else if (e < 184320) {
    e -= 163840;
    const int n = e >> 7, k = e & 127;
    BqT[e] = f2bf(n < 32 ? key_mem[n * 128 + k] : W_df1[k * 128 + (n - 32)]);
  }
}

// ============================================================
// kErAdd (FUSED): both erase and add per block; A gathered once.
// grid (BSN/128), block 256. LDS 48 KB -> 3 blocks/CU. (unchanged)
// ============================================================
__global__ __launch_bounds__(256) void kErAdd(
    const int* __restrict__ qa_data, const float* __restrict__ qa_table,
    const u16* __restrict__ WerT, const u16* __restrict__ WaddT,
    const float* __restrict__ b_er, const float* __restrict__ b_ad,
    u16* __restrict__ eras, u16* __restrict__ addb)
{
  __shared__ __align__(16) u16 As[4 * 128 * 32];   // [chunk][m][k'] 32 KB
  __shared__ __align__(16) u16 Bs[2 * 128 * 32];   // dbuf [n][k'] 16 KB
  const int tid = threadIdx.x;
  const int p0  = blockIdx.x * 128;

  {
    const int r = tid >> 1, h = tid & 1;
    const long base = (long)qa_data[p0 + r] * DVN + h * 64;
    #pragma unroll
    for (int g = 0; g < 8; ++g) {
      const int k0 = h * 64 + g * 8;
      const float4 fa = *(const float4*)(qa_table + base + g * 8);
      const float4 fb = *(const float4*)(qa_table + base + g * 8 + 4);
      uint4 pk;
      pk.x = pack2(fa.x, fa.y); pk.y = pack2(fa.z, fa.w);
      pk.z = pack2(fb.x, fb.y); pk.w = pack2(fb.z, fb.w);
      *(uint4*)(As + (k0 >> 5) * 4096 + r * 32 + (k0 & 31)) = pk;
    }
  }

  const int lane = tid & 63, wave = tid >> 6;
  const int wr = (wave >> 1) * 64, wc = (wave & 1) * 64;
  const int c15 = lane & 15, q = lane >> 4;

  for (int sel = 0; sel < 2; ++sel) {
    const u16*   Wt = sel ? WaddT : WerT;
    const float* bb = sel ? b_ad  : b_er;
    u16*       outp = sel ? addb  : eras;

    {
      #pragma unroll
      for (int u = 0; u < 2; ++u) {
        const int f = tid + 256 * u;
        const int n = f >> 2, j = f & 3;
        *(uint4*)(Bs + n * 32 + j * 8) = *(const uint4*)(Wt + n * 128 + j * 8);
      }
    }
    __syncthreads();

    f32x4 acc[4][4];
    #pragma unroll
    for (int b = 0; b < 4; ++b) {
      const float bv = bb[wc + 16 * b + c15];
      #pragma unroll
      for (int a = 0; a < 4; ++a) acc[a][b] = (f32x4){bv, bv, bv, bv};
    }

    for (int c = 0; c < 4; ++c) {
      const int cur = c & 1;
      uint4 st[2];
      const bool more = (c + 1 < 4);
      if (more) {
        #pragma unroll
        for (int u = 0; u < 2; ++u) {
          const int f = tid + 256 * u;
          const int n = f >> 2, j = f & 3;
          st[u] = *(const uint4*)(Wt + n * 128 + (c + 1) * 32 + j * 8);
        }
      }
      bf16x8 af[4], bf[4];
      #pragma unroll
      for (int a = 0; a < 4; ++a)
        af[a] = *(const bf16x8*)(As + c * 4096 + (wr + 16 * a + c15) * 32 + q * 8);
      #pragma unroll
      for (int b = 0; b < 4; ++b)
        bf[b] = *(const bf16x8*)(Bs + cur * 4096 + (wc + 16 * b + c15) * 32 + q * 8);
      #pragma unroll
      for (int a = 0; a < 4; ++a)
        #pragma unroll
        for (int b = 0; b < 4; ++b)
          acc[a][b] = __builtin_amdgcn_mfma_f32_16x16x32_bf16(af[a], bf[b], acc[a][b], 0, 0, 0);
      if (more) {
        #pragma unroll
        for (int u = 0; u < 2; ++u) {
          const int f = tid + 256 * u;
          const int n = f >> 2, j = f & 3;
          *(uint4*)(Bs + (cur ^ 1) * 4096 + n * 32 + j * 8) = st[u];
        }
      }
      __syncthreads();
    }

    const int colb = wc + c15;
    #pragma unroll
    for (int a = 0; a < 4; ++a) {
      #pragma unroll
      for (int r = 0; r < 4; ++r) {
        const int row = p0 + wr + 16 * a + 4 * q + r;
        u16* yp = outp + (long)row * DVN + colb;
        #pragma unroll
        for (int b = 0; b < 4; ++b) {
          const float v = sel ? tanh_fast(acc[a][b][r]) : sigmoid_fast(acc[a][b][r]);
          yp[16 * b] = f2bf(v);
        }
      }
    }
  }
}

// ============================================================
// kQe (MFMA): qe[128x128] @ BqT^T[128x160]; softmax + diff head.
// (unchanged)
// ============================================================
__global__ __launch_bounds__(256) void kQe(
    const int* __restrict__ q_data, const float* __restrict__ q_table,
    const u16* __restrict__ BqT,
    const float* __restrict__ bdf1, const float* __restrict__ Wdf2,
    const float* __restrict__ bdf2,
    float* __restrict__ w_all, float* __restrict__ diff,
    u16* __restrict__ sin_buf)
{
  __shared__ __align__(16) u16 As[4 * 128 * 32];   // 32 KB
  __shared__ __align__(16) u16 Bs[4 * 160 * 32];   // 40 KB
  const int tid = threadIdx.x;
  const int p0  = blockIdx.x * 128;

  {
    const int r = tid >> 1, h = tid & 1;
    const long base = (long)q_data[p0 + r] * DKN + h * 64;
    #pragma unroll
    for (int g = 0; g < 8; ++g) {
      const int k0 = h * 64 + g * 8;
      const float4 fa = *(const float4*)(q_table + base + g * 8);
      const float4 fb = *(const float4*)(q_table + base + g * 8 + 4);
      uint4 pk;
      pk.x = pack2(fa.x, fa.y); pk.y = pack2(fa.z, fa.w);
      pk.z = pack2(fb.x, fb.y); pk.w = pack2(fb.z, fb.w);
      *(uint4*)(As + (k0 >> 5) * 4096 + r * 32 + (k0 & 31)) = pk;
      *(uint4*)(sin_buf + (long)(p0 + r) * DSN + DKN + k0) = pk;
    }
  }
  {
    #pragma unroll
    for (int u = 0; u < 10; ++u) {
      const int f = tid + 256 * u;
      const int n = f >> 4, jj = f & 15;
      *(uint4*)(Bs + (jj >> 2) * 5120 + n * 32 + (jj & 3) * 8) =
          *(const uint4*)(BqT + n * 128 + jj * 8);
    }
  }
  __syncthreads();

  const int lane = tid & 63, wave = tid >> 6;
  const int wr = (wave >> 1) * 64, wc = (wave & 1) * 80;
  const int c15 = lane & 15, q = lane >> 4;

  f32x4 acc[4][5];
  float w2v[5];
  #pragma unroll
  for (int b = 0; b < 5; ++b) {
    const int col = wc + 16 * b + c15;
    const float bv = (col < 32) ? 0.f : bdf1[col - 32];
    w2v[b] = (col < 32) ? 0.f : Wdf2[col - 32];
    #pragma unroll
    for (int a = 0; a < 4; ++a) acc[a][b] = (f32x4){bv, bv, bv, bv};
  }

  #pragma unroll
  for (int c = 0; c < 4; ++c) {
    bf16x8 af[4], bf[5];
    #pragma unroll
    for (int a = 0; a < 4; ++a)
      af[a] = *(const bf16x8*)(As + c * 4096 + (wr + 16 * a + c15) * 32 + q * 8);
    #pragma unroll
    for (int b = 0; b < 5; ++b)
      bf[b] = *(const bf16x8*)(Bs + c * 5120 + (wc + 16 * b + c15) * 32 + q * 8);
    #pragma unroll
    for (int a = 0; a < 4; ++a)
      #pragma unroll
      for (int b = 0; b < 5; ++b)
        acc[a][b] = __builtin_amdgcn_mfma_f32_16x16x32_bf16(af[a], bf[b], acc[a][b], 0, 0, 0);
  }

  if (wc == 0) {
    #pragma unroll
    for (int a = 0; a < 4; ++a) {
      #pragma unroll
      for (int r = 0; r < 4; ++r) {
        float s0 = acc[a][0][r], s1 = acc[a][1][r];
        float mx = fmaxf(s0, s1);
        mx = fmaxf(mx, __shfl_xor(mx, 1, 64));
        mx = fmaxf(mx, __shfl_xor(mx, 2, 64));
        mx = fmaxf(mx, __shfl_xor(mx, 4, 64));
        mx = fmaxf(mx, __shfl_xor(mx, 8, 64));
        const float e0 = __expf(s0 - mx), e1 = __expf(s1 - mx);
        float sm = e0 + e1;
        sm += __shfl_xor(sm, 1, 64);
        sm += __shfl_xor(sm, 2, 64);
        sm += __shfl_xor(sm, 4, 64);
        sm += __shfl_xor(sm, 8, 64);
        const float inv = 1.f / sm;
        const int row = p0 + wr + 16 * a + 4 * q + r;
        w_all[(long)row * MEMN + c15]      = e0 * inv;
        w_all[(long)row * MEMN + 16 + c15] = e1 * inv;
      }
    }
  }

  float sv[4][4];
  #pragma unroll
  for (int a = 0; a < 4; ++a) {
    #pragma unroll
    for (int r = 0; r < 4; ++r) {
      float s = 0.f;
      #pragma unroll
      for (int b = 0; b < 5; ++b)
        s = fmaf(tanh_fast(acc[a][b][r]), w2v[b], s);
      s += __shfl_xor(s, 1, 64);
      s += __shfl_xor(s, 2, 64);
      s += __shfl_xor(s, 4, 64);
      s += __shfl_xor(s, 8, 64);
      sv[a][r] = s;
    }
  }
  __syncthreads();
  float* red = (float*)As;
  if ((wave & 1) && c15 == 0) {
    #pragma unroll
    for (int a = 0; a < 4; ++a)
      #pragma unroll
      for (int r = 0; r < 4; ++r)
        red[wr + 16 * a + 4 * q + r] = sv[a][r];
  }
  __syncthreads();
  if (!(wave & 1) && c15 == 0) {
    const float bd = bdf2[0];
    #pragma unroll
    for (int a = 0; a < 4; ++a)
      #pragma unroll
      for (int r = 0; r < 4; ++r) {
        const int rr = wr + 16 * a + 4 * q + r;
        diff[p0 + rr] = sv[a][r] + red[rr] + bd;
      }
  }
}

// ============================================================
// kScan v6 (unchanged from round 12: deferred reduction)
// ============================================================
#define CHUNK_BYTES 12288
#define PB_OFF      25088     // 2*CHUNK_BYTES + 512

#define KSTAGE(K, BUF)                                                        \
  {                                                                           \
    const char* wsrc = (const char*)(w_all + (pbase + (long)(K) * 32) * MEMN);\
    const char* esrc = (const char*)(eras + (pbase + (long)(K) * 32) * DVN)   \
                       + ch * 128;                                            \
    const char* asrc = (const char*)(addb + (pbase + (long)(K) * 32) * DVN)   \
                       + ch * 128;                                            \
    char* dst = lds + (BUF) * CHUNK_BYTES;                                    \
    _Pragma("unroll")                                                         \
    for (int r = 0; r < 3; ++r) {                                             \
      const int o = (tid + r * 256) * 16;                                     \
      const char* src;                                                        \
      if (o < 4096) {                                                         \
        src = wsrc + o;                                                       \
      } else if (o < 8192) {                                                  \
        const int f = o - 4096;                                               \
        src = esrc + (f >> 7) * 256 + (f & 127);                              \
      } else {                                                                \
        const int f = o - 8192;                                               \
        src = asrc + (f >> 7) * 256 + (f & 127);                              \
      }                                                                       \
      GLOAD_LDS16(src, dst + o);                                              \
    }                                                                         \
  }

__global__ __launch_bounds__(256) void kScan(
    const float* __restrict__ w_all, const u16* __restrict__ eras,
    const u16* __restrict__ addb, const float* __restrict__ init_mem,
    u16* __restrict__ sin_buf)
{
  __shared__ __align__(16) char lds[PB_OFF + 32768];
  const int tid = threadIdx.x;
  const int ch  = blockIdx.x & 1;
  const int lc  = tid >> 2;
  const int gc  = ch * 64 + lc;
  const int h   = tid & 3;
  const long pbase = (long)(blockIdx.x >> 1) * S_N;

  float* pb = (float*)(lds + PB_OFF);

  float Mv[8];
  #pragma unroll
  for (int m = 0; m < 8; ++m) Mv[m] = init_mem[(h * 8 + m) * DVN + gc];

  const int lc2  = tid & 63;
  const int sblk = tid >> 6;
  u16* sp2 = sin_buf + pbase * DSN + ch * 64 + lc2;

  KSTAGE(0, 0)
  for (int k = 0; k < 16; ++k) {
    __syncthreads();
    if (k + 1 < 16) KSTAGE(k + 1, (k + 1) & 1)

    const char*  wb  = lds + (k & 1) * CHUNK_BYTES;
    const f32x4* wl4 = (const f32x4*)wb;
    const u16*   el  = (const u16*)(wb + 4096);
    const u16*   al  = (const u16*)(wb + 8192);

    f32x4 Wr[3][2];
    u16 er[3], ar[3];
    #pragma unroll
    for (int i = 0; i < 2; ++i) Wr[0][i] = wl4[h * 2 + i];
    er[0] = el[lc]; ar[0] = al[lc];
    #pragma unroll
    for (int i = 0; i < 2; ++i) Wr[1][i] = wl4[8 + h * 2 + i];
    er[1] = el[64 + lc]; ar[1] = al[64 + lc];

    #pragma unroll
    for (int s = 0; s < 32; ++s) {
      const int cur = s % 3, nx2 = (s + 2) % 3;
      Wr[nx2][0] = wl4[(s + 2) * 8 + h * 2];
      Wr[nx2][1] = wl4[(s + 2) * 8 + h * 2 + 1];
      er[nx2] = el[(s + 2) * 64 + lc];
      ar[nx2] = al[(s + 2) * 64 + lc];
      {
        float ac0 = 0.f, ac1 = 0.f, ac2 = 0.f, ac3 = 0.f;
        #pragma unroll
        for (int i = 0; i < 2; ++i) {
          ac0 = fmaf(Wr[cur][i][0], Mv[4 * i + 0], ac0);
          ac1 = fmaf(Wr[cur][i][1], Mv[4 * i + 1], ac1);
          ac2 = fmaf(Wr[cur][i][2], Mv[4 * i + 2], ac2);
          ac3 = fmaf(Wr[cur][i][3], Mv[4 * i + 3], ac3);
        }
        pb[s * 256 + lc * 4 + h] = (ac0 + ac1) + (ac2 + ac3);
        const float ec = bf2f(er[cur]);
        const float an = -bf2f(ar[cur]);
        #pragma unroll
        for (int i = 0; i < 2; ++i) {
          #pragma unroll
          for (int j = 0; j < 4; ++j) {
            const float t = fmaf(ec, Mv[4 * i + j], an);
            Mv[4 * i + j] = fmaf(-Wr[cur][i][j], t, Mv[4 * i + j]);
          }
        }
      }
    }

    __syncthreads();
    const int lb = k * 32;
    #pragma unroll
    for (int r = 0; r < 8; ++r) {
      const int s = sblk * 8 + r;
      const f32x4 pv = *(const f32x4*)(pb + s * 256 + lc2 * 4);
      sp2[(long)(lb + s) * DSN] = f2bf((pv[0] + pv[1]) + (pv[2] + pv[3]));
    }
  }
}

// ============================================================
// kSum v2 (m97-style): per-chunk double-buffered async staging.
// A and B chunks each used once -> stream them. LDS = 2 x (A 8KB +
// B 8KB) = 32 KB -> ~4-5 blocks/CU (was 80 KB / 2 blocks).
// grid (BSN/128, 2: col half), block 256.
// ============================================================
#define SSTAGE(XP, WP, C, BUF)                                              \
  {                                                                         \
    _Pragma("unroll")                                                       \
    for (int u = 0; u < 2; ++u) {                                           \
      const int idx = tid + 256 * u;                                        \
      const int row = idx >> 2, k8 = idx & 3;                               \
      GLOAD_LDS16(XP + (long)(p0 + row) * DSN + (C) * 32 + k8 * 8,          \
                  Ls + (BUF) * 8192 + idx * 8);                             \
      GLOAD_LDS16(WP + (long)(j0 + row) * 256 + (C) * 32 + k8 * 8,          \
                  Ls + (BUF) * 8192 + 4096 + idx * 8);                      \
    }                                                                       \
  }

__global__ __launch_bounds__(256) void kSum(
    const u16* __restrict__ X, const u16* __restrict__ WsumT,
    const float* __restrict__ bias, u16* __restrict__ Y)
{
  __shared__ __align__(16) u16 Ls[2 * 8192];   // 32 KB: [buf][A 4096 | B 4096]
  const int tid = threadIdx.x;
  const int p0  = blockIdx.x * 128;
  const int j0  = blockIdx.y * 128;

  const int lane = tid & 63, wave = tid >> 6;
  const int wr = (wave >> 1) * 64, wc = (wave & 1) * 64;
  const int c15 = lane & 15, q = lane >> 4;

  f32x4 acc[4][4];
  #pragma unroll
  for (int b = 0; b < 4; ++b) {
    const float bv = bias[j0 + wc + 16 * b + c15];
    #pragma unroll
    for (int a = 0; a < 4; ++a) acc[a][b] = (f32x4){bv, bv, bv, bv};
  }

  SSTAGE(X, WsumT, 0, 0)
  for (int c = 0; c < 8; ++c) {
    __syncthreads();                         // chunk c staged (vmcnt drained)
    if (c + 1 < 8) SSTAGE(X, WsumT, c + 1, (c + 1) & 1)

    const u16* Ab = Ls + (c & 1) * 8192;
    const u16* Bb = Ab + 4096;
    bf16x8 af[4], bf[4];
    #pragma unroll
    for (int a = 0; a < 4; ++a)
      af[a] = *(const bf16x8*)(Ab + (wr + 16 * a + c15) * 32 + q * 8);
    #pragma unroll
    for (int b = 0; b < 4; ++b)
      bf[b] = *(const bf16x8*)(Bb + (wc + 16 * b + c15) * 32 + q * 8);
    #pragma unroll
    for (int a = 0; a < 4; ++a)
      #pragma unroll
      for (int b = 0; b < 4; ++b)
        acc[a][b] = __builtin_amdgcn_mfma_f32_16x16x32_bf16(af[a], bf[b], acc[a][b], 0, 0, 0);
  }

  const int colb = j0 + wc + c15;
  #pragma unroll
  for (int a = 0; a < 4; ++a) {
    #pragma unroll
    for (int r = 0; r < 4; ++r) {
      const int row = p0 + wr + 16 * a + 4 * q + r;
      u16* yp = Y + (long)row * DSN + colb;
      #pragma unroll
      for (int b = 0; b < 4; ++b)
        yp[16 * b] = f2bf(tanh_fast(acc[a][b][r]));
    }
  }
}

// ============================================================
// kAb v2 (m97-style) + fused W_ab2 dot. Same staging as kSum v2.
// ============================================================
__global__ __launch_bounds__(256) void kAb(
    const u16* __restrict__ X, const u16* __restrict__ Wab1T,
    const float* __restrict__ bias, const float* __restrict__ Wab2,
    float* __restrict__ part)
{
  __shared__ __align__(16) u16 Ls[2 * 8192];   // 32 KB
  const int tid = threadIdx.x;
  const int p0  = blockIdx.x * 128;
  const int j0  = blockIdx.y * 128;

  const int lane = tid & 63, wave = tid >> 6;
  const int wr = (wave >> 1) * 64, wc = (wave & 1) * 64;
  const int c15 = lane & 15, q = lane >> 4;

  f32x4 acc[4][4];
  float w2v[4];
  #pragma unroll
  for (int b = 0; b < 4; ++b) {
    const int col = j0 + wc + 16 * b + c15;
    const float bv = bias[col];
    w2v[b] = Wab2[col];
    #pragma unroll
    for (int a = 0; a < 4; ++a) acc[a][b] = (f32x4){bv, bv, bv, bv};
  }

  SSTAGE(X, Wab1T, 0, 0)
  for (int c = 0; c < 8; ++c) {
    __syncthreads();
    if (c + 1 < 8) SSTAGE(X, Wab1T, c + 1, (c + 1) & 1)

    const u16* Ab = Ls + (c & 1) * 8192;
    const u16* Bb = Ab + 4096;
    bf16x8 af[4], bf[4];
    #pragma unroll
    for (int a = 0; a < 4; ++a)
      af[a] = *(const bf16x8*)(Ab + (wr + 16 * a + c15) * 32 + q * 8);
    #pragma unroll
    for (int b = 0; b < 4; ++b)
      bf[b] = *(const bf16x8*)(Bb + (wc + 16 * b + c15) * 32 + q * 8);
    #pragma unroll
    for (int a = 0; a < 4; ++a)
      #pragma unroll
      for (int b = 0; b < 4; ++b)
        acc[a][b] = __builtin_amdgcn_mfma_f32_16x16x32_bf16(af[a], bf[b], acc[a][b], 0, 0, 0);
  }

  // epilogue: tanh + W_ab2 dot, reduce 16 col-lanes, pair waves via LDS.
  float sv[4][4];
  #pragma unroll
  for (int a = 0; a < 4; ++a) {
    #pragma unroll
    for (int r = 0; r < 4; ++r) {
      float s = 0.f;
      #pragma unroll
      for (int b = 0; b < 4; ++b)
        s = fmaf(tanh_fast(acc[a][b][r]), w2v[b], s);
      s += __shfl_xor(s, 1, 64);
      s += __shfl_xor(s, 2, 64);
      s += __shfl_xor(s, 4, 64);
      s += __shfl_xor(s, 8, 64);
      sv[a][r] = s;
    }
  }
  __syncthreads();             // all waves past last mfma; Ls free
  float* red = (float*)Ls;     // 128 f32
  if ((wave & 1) && c15 == 0) {
    #pragma unroll
    for (int a = 0; a < 4; ++a)
      #pragma unroll
      for (int r = 0; r < 4; ++r)
        red[wr + 16 * a + 4 * q + r] = sv[a][r];
  }
  __syncthreads();
  if (!(wave & 1) && c15 == 0) {
    #pragma unroll
    for (int a = 0; a < 4; ++a)
      #pragma unroll
      for (int r = 0; r < 4; ++r) {
        const int rr = wr + 16 * a + 4 * q + r;
        part[(long)blockIdx.y * BSN + p0 + rr] = sv[a][r] + red[rr];
      }
  }
}

// ============================================================
// kOut: combine. grid (BSN/256), block 256. f32 output.
// ============================================================
__global__ __launch_bounds__(256) void kOut(
    const float* __restrict__ part, const float* __restrict__ diff,
    const float* __restrict__ bab2, float* __restrict__ out)
{
  const int p = blockIdx.x * 256 + threadIdx.x;
  const float ab = part[p] + part[BSN + p] + bab2[0];
  const float d  = diff[p];
  const float z  = 3.0f * ab - d;
  out[p]           = sigmoid_fast(z);
  out[BSN + p]     = ab;
  out[2 * BSN + p] = d;
  out[3 * BSN + p] = z;
}

// ============================================================
// launch
// ============================================================
extern "C" void kernel_launch(void* const* d_in, const int* in_sizes, int n_in,
                              void* d_out, int out_size, void* d_ws, size_t ws_size,
                              hipStream_t stream)
{
  const int*   q_data   = (const int*)d_in[0];
  const int*   qa_data  = (const int*)d_in[1];
  const float* q_table  = (const float*)d_in[2];
  const float* qa_table = (const float*)d_in[3];
  const float* key_mem  = (const float*)d_in[4];
  const float* init_mem = (const float*)d_in[5];
  const float* W_erase  = (const float*)d_in[6];
  const float* b_erase  = (const float*)d_in[7];
  const float* W_add    = (const float*)d_in[8];
  const float* b_add    = (const float*)d_in[9];
  const float* W_sum    = (const float*)d_in[10];
  const float* b_sum    = (const float*)d_in[11];
  const float* W_ab1    = (const float*)d_in[12];
  const float* b_ab1    = (const float*)d_in[13];
  const float* W_ab2    = (const float*)d_in[14];
  const float* b_ab2    = (const float*)d_in[15];
  const float* W_df1    = (const float*)d_in[16];
  const float* b_df1    = (const float*)d_in[17];
  const float* W_df2    = (const float*)d_in[18];
  const float* b_df2    = (const float*)d_in[19];

  // workspace layout (bytes); total 152,936,448
  char* ws = (char*)d_ws;
  float* w_all = (float*)(ws + 0);           // [BS][32] f32   16,777,216
  u16*   eras  = (u16*)(ws + 16777216);      // [BS][128] bf16 33,554,432
  u16*   addb  = (u16*)(ws + 50331648);      // [BS][128] bf16 33,554,432
  u16*   sinb  = (u16*)(ws + 83886080);      // [BS][256] bf16 67,108,864
  float* diffb = (float*)(ws + 150994944);   // [BS] f32          524,288
  float* part  = (float*)(ws + 151519232);   // [2][BS] f32     1,048,576
  u16*   WerT  = (u16*)(ws + 152567808);     // 32,768
  u16*   WaddT = (u16*)(ws + 152600576);     // 32,768
  u16*   WsumT = (u16*)(ws + 152633344);     // 131,072
  u16*   Wab1T = (u16*)(ws + 152764416);     // 131,072
  u16*   BqT   = (u16*)(ws + 152895488);     // 160x128 bf16 = 40,960
  u16*   summ  = eras;                       // summary reuses eras+addb

  kPrep<<<dim3(720), 256, 0, stream>>>(W_sum, W_ab1, W_erase, W_add, key_mem, W_df1,
                                       WsumT, Wab1T, WerT, WaddT, BqT);
  kErAdd<<<dim3(BSN / 128), 256, 0, stream>>>(qa_data, qa_table, WerT, WaddT,
                                              b_erase, b_add, eras, addb);
  kQe<<<dim3(BSN / 128), 256, 0, stream>>>(q_data, q_table, BqT, b_df1, W_df2, b_df2,
                                           w_all, diffb, sinb);
  kScan<<<dim3(B_N * 2), 256, 0, stream>>>(w_all, eras, addb, init_mem, sinb);
  kSum<<<dim3(BSN / 128, 2), 256, 0, stream>>>(sinb, WsumT, b_sum, summ);
  kAb<<<dim3(BSN / 128, 2), 256, 0, stream>>>(summ, Wab1T, b_ab1, W_ab2, part);
  kOut<<<dim3(BSN / 256), 256, 0, stream>>>(part, diffb, b_ab2, (float*)d_out);
}